// Round 1
// 773.040 us; speedup vs baseline: 1.0097x; 1.0097x over previous
//
#include <hip/hip_runtime.h>

// Problem constants (B=4, L=4096, D=1024 fixed by the reference setup)
#define B_ 4
#define L_ 4096
#define D_ 1024
#define M_ (B_*L_)              // 16384 rows
#define LC 64                   // scan chunk length
#define NC (L_/LC)              // 64 chunks
#define SLOT ((size_t)M_*D_)    // elements per output slot (16,777,216)

typedef __attribute__((ext_vector_type(4))) float f4;
typedef __bf16 bf16x8 __attribute__((ext_vector_type(8)));

__device__ __forceinline__ unsigned short f2bf(float f) {
  unsigned int u = __float_as_uint(f);
  u += 0x7FFFu + ((u >> 16) & 1u);         // round-to-nearest-even
  return (unsigned short)(u >> 16);
}
__device__ __forceinline__ float sigmoidf_(float x) { return 1.f / (1.f + __expf(-x)); }
__device__ __forceinline__ float siluf_(float x)    { return x / (1.f + __expf(-x)); }

// ---------------- weight transpose + fp32->bf16 convert -------------------
// W [K=1024][N=1024] row-major fp32  ->  Wt [N][K] bf16 (B^T layout for GEMM)
__global__ __launch_bounds__(256) void transpose_cvt(
    const float* __restrict__ Wa, const float* __restrict__ Wb,
    const float* __restrict__ Wc,
    unsigned short* __restrict__ Wab, unsigned short* __restrict__ Wct) {
  __shared__ float tile[32][33];
  const float* src = (blockIdx.z == 0) ? Wa : (blockIdx.z == 1 ? Wb : Wc);
  unsigned short* dst = (blockIdx.z == 2) ? Wct
                        : (Wab + (blockIdx.z == 1 ? (size_t)D_*D_ : 0));
  int n = blockIdx.x*32 + threadIdx.x;     // source col
  int k0 = blockIdx.y*32;                  // source row base
  for (int i = threadIdx.y; i < 32; i += 8)
    tile[i][threadIdx.x] = src[(size_t)(k0+i)*D_ + n];
  __syncthreads();
  int k = k0 + threadIdx.x;
  int n0 = blockIdx.x*32;
  for (int i = threadIdx.y; i < 32; i += 8)
    dst[(size_t)(n0+i)*D_ + k] = f2bf(tile[threadIdx.x][i]);
}

// ---------------- RMSNorm -> bf16 ----------------------------------------
__global__ __launch_bounds__(256) void rmsnorm_bf16(
    const float* __restrict__ ctx, const float* __restrict__ g,
    unsigned short* __restrict__ out) {
  const size_t row = blockIdx.x;
  const int t = threadIdx.x;
  f4 xv = ((const f4*)(ctx + row*D_))[t];
  float ss = xv.x*xv.x + xv.y*xv.y + xv.z*xv.z + xv.w*xv.w;
  #pragma unroll
  for (int o = 32; o > 0; o >>= 1) ss += __shfl_down(ss, o);
  __shared__ float red[4];
  if ((t & 63) == 0) red[t >> 6] = ss;
  __syncthreads();
  float tot = red[0] + red[1] + red[2] + red[3];
  float sc = rsqrtf(tot * (1.f/(float)D_) + 1e-6f);
  f4 gv = ((const f4*)g)[t];
  f4 y = xv * sc * gv;
  ushort4 o4; o4.x = f2bf(y.x); o4.y = f2bf(y.y); o4.z = f2bf(y.z); o4.w = f2bf(y.w);
  ((ushort4*)out)[row*(D_/4) + t] = o4;
}

// ---------------- bf16 MFMA GEMM kernels ----------------------------------
#define BM 128
#define BN 128
#define BK 32

// Fused dual-weight GEMM: per block, 128x64 tile of A@Wa^T AND A@Wb^T sharing
// one A staging. Epilogue computes alpha=sigmoid, beta=silu,
// x = v*beta*sqrt(clip(1-alpha^2)), and the v passthrough -- replaces the old
// N=2048 gemm + make_x + v memcpy (saves ~192 MB HBM + 2 launches).
// Per-K-iter cost identical to the proven m97-structure kernel:
// 4 global_load_lds/wave, 8 ds_read_b128/wave, 16 MFMA/wave, 16 KB LDS.
__global__ __launch_bounds__(256) void gemm_ab(
    const unsigned short* __restrict__ A, const unsigned short* __restrict__ Wab,
    const float* __restrict__ b_alpha, const float* __restrict__ b_beta,
    const float* __restrict__ v,
    float* __restrict__ alphas, float* __restrict__ x, float* __restrict__ v_out) {
  __shared__ unsigned short As[BM*BK];     // [128][32], 8 KB
  __shared__ unsigned short Bs[2*64*BK];   // B0 tile [64][32] | B1 tile [64][32], 8 KB
  const int tid  = threadIdx.x;
  const int wave = tid >> 6;
  const int lane = tid & 63;
  const int q    = lane >> 4;              // quad 0..3
  const int l16  = lane & 15;
  const int wm   = (wave >> 1) * 64;       // wave m-half in 128
  const int wn   = (wave & 1) * 32;        // wave n-half in 64

  const int bx = blockIdx.x;               // 16 n-tiles of 64
  const int by = blockIdx.y;               // 128 m-tiles of 128

  // staging: waves 0..3 stage A rows [wave*32, wave*32+32);
  // waves 0,1 stage B0 (Wa^T) rows, waves 2,3 stage B1 (Wb^T) rows.
  const unsigned short* Ag = A + ((size_t)by*BM + wave*32 + (lane>>2)) * D_ + (lane&3)*8;
  const int bsel = wave >> 1;              // which weight this wave stages
  const unsigned short* Bg = Wab + ((size_t)bsel*D_ + bx*64 + (wave&1)*32 + (lane>>2)) * D_ + (lane&3)*8;
  unsigned short* AsW = As + wave*1024;
  unsigned short* BsW = Bs + bsel*2048 + (wave&1)*1024;

  f4 acc[4][2][2] = {};                    // [m-frag][n-frag][weight]

  for (int kt = 0; kt < D_; kt += BK) {
    __builtin_amdgcn_global_load_lds((const __attribute__((address_space(1))) void*)(Ag + kt),
                                     (__attribute__((address_space(3))) void*)(AsW), 16, 0, 0);
    __builtin_amdgcn_global_load_lds((const __attribute__((address_space(1))) void*)(Ag + kt + 16*D_),
                                     (__attribute__((address_space(3))) void*)(AsW + 512), 16, 0, 0);
    __builtin_amdgcn_global_load_lds((const __attribute__((address_space(1))) void*)(Bg + kt),
                                     (__attribute__((address_space(3))) void*)(BsW), 16, 0, 0);
    __builtin_amdgcn_global_load_lds((const __attribute__((address_space(1))) void*)(Bg + kt + 16*D_),
                                     (__attribute__((address_space(3))) void*)(BsW + 512), 16, 0, 0);
    __syncthreads();

    bf16x8 af[4], bf0[2], bf1[2];
    #pragma unroll
    for (int i = 0; i < 4; ++i)
      af[i] = *(const bf16x8*)&As[(wm + i*16 + l16)*BK + q*8];
    #pragma unroll
    for (int j = 0; j < 2; ++j) {
      bf0[j] = *(const bf16x8*)&Bs[(wn + j*16 + l16)*BK + q*8];
      bf1[j] = *(const bf16x8*)&Bs[2048 + (wn + j*16 + l16)*BK + q*8];
    }
    #pragma unroll
    for (int i = 0; i < 4; ++i)
      #pragma unroll
      for (int j = 0; j < 2; ++j) {
        acc[i][j][0] = __builtin_amdgcn_mfma_f32_16x16x32_bf16(af[i], bf0[j], acc[i][j][0], 0, 0, 0);
        acc[i][j][1] = __builtin_amdgcn_mfma_f32_16x16x32_bf16(af[i], bf1[j], acc[i][j][1], 0, 0, 0);
      }
    __syncthreads();
  }

  // C/D layout: row = q*4 + reg, col = l16
  const int mbase = by*BM + wm + q*4;
  const int nbase = bx*64 + wn + l16;
  #pragma unroll
  for (int j = 0; j < 2; ++j) {
    const int n = nbase + j*16;
    const float ba = b_alpha[n];
    const float bb = b_beta[n];
    #pragma unroll
    for (int i = 0; i < 4; ++i)
      #pragma unroll
      for (int r = 0; r < 4; ++r) {
        const int m = mbase + i*16 + r;
        const size_t idx = (size_t)m*D_ + n;
        float al = sigmoidf_(acc[i][j][0][r] + ba);
        float be = siluf_(acc[i][j][1][r] + bb);
        float vv = v[idx];
        float ws = sqrtf(fmaxf(1.f - al*al, 1e-6f));
        alphas[idx] = al;
        x[idx]      = vv * be * ws;
        v_out[idx]  = vv;
      }
  }
}

// Single-weight GEMM (m97 structure, unchanged) for the ctx projection.
template<typename Epi>
__global__ __launch_bounds__(256) void gemm128(
    const unsigned short* __restrict__ A, const unsigned short* __restrict__ Bt,
    Epi epi) {
  __shared__ unsigned short As[BM*BK];
  __shared__ unsigned short Bs[BN*BK];
  const int tid  = threadIdx.x;
  const int wave = tid >> 6;
  const int lane = tid & 63;
  const int q    = lane >> 4;
  const int l16  = lane & 15;
  const int wm   = (wave >> 1) * 64;
  const int wn   = (wave & 1) * 64;

  const unsigned short* Ag = A  + ((size_t)blockIdx.y*BM + wave*32 + (lane>>2)) * D_ + (lane&3)*8;
  const unsigned short* Bg = Bt + ((size_t)blockIdx.x*BN + wave*32 + (lane>>2)) * D_ + (lane&3)*8;
  unsigned short* AsW = As + wave*1024;
  unsigned short* BsW = Bs + wave*1024;

  f4 acc[4][4] = {};

  for (int kt = 0; kt < D_; kt += BK) {
    __builtin_amdgcn_global_load_lds((const __attribute__((address_space(1))) void*)(Ag + kt),
                                     (__attribute__((address_space(3))) void*)(AsW), 16, 0, 0);
    __builtin_amdgcn_global_load_lds((const __attribute__((address_space(1))) void*)(Ag + kt + 16*D_),
                                     (__attribute__((address_space(3))) void*)(AsW + 512), 16, 0, 0);
    __builtin_amdgcn_global_load_lds((const __attribute__((address_space(1))) void*)(Bg + kt),
                                     (__attribute__((address_space(3))) void*)(BsW), 16, 0, 0);
    __builtin_amdgcn_global_load_lds((const __attribute__((address_space(1))) void*)(Bg + kt + 16*D_),
                                     (__attribute__((address_space(3))) void*)(BsW + 512), 16, 0, 0);
    __syncthreads();

    bf16x8 af[4], bfr[4];
    #pragma unroll
    for (int i = 0; i < 4; ++i)
      af[i] = *(const bf16x8*)&As[(wm + i*16 + l16)*BK + q*8];
    #pragma unroll
    for (int j = 0; j < 4; ++j)
      bfr[j] = *(const bf16x8*)&Bs[(wn + j*16 + l16)*BK + q*8];
    #pragma unroll
    for (int i = 0; i < 4; ++i)
      #pragma unroll
      for (int j = 0; j < 4; ++j)
        acc[i][j] = __builtin_amdgcn_mfma_f32_16x16x32_bf16(af[i], bfr[j], acc[i][j], 0, 0, 0);
    __syncthreads();
  }

  const int mbase = blockIdx.y*BM + wm + q*4;
  const int nbase = blockIdx.x*BN + wn + l16;
  #pragma unroll
  for (int i = 0; i < 4; ++i)
    #pragma unroll
    for (int j = 0; j < 4; ++j)
      #pragma unroll
      for (int r = 0; r < 4; ++r)
        epi(mbase + i*16 + r, nbase + j*16, acc[i][j][r]);
}

struct EpiCtx {
  const float* b_ctx; const float* ctx_in; float* ctx_out;
  __device__ void operator()(int m, int n, float c) const {
    size_t idx = (size_t)m*D_ + n;
    ctx_out[idx] = ctx_in[idx] + siluf_(c + b_ctx[n]);
  }
};

// ---------------- chunked linear recurrence --------------------------------
// pass1: per-chunk summaries (A_prod, h_end)
__global__ __launch_bounds__(256) void scan_pass1(
    const float* __restrict__ x, const float* __restrict__ a,
    float* __restrict__ sumA, float* __restrict__ sumH) {
  const int c = blockIdx.x, b = blockIdx.y;
  const int t4 = threadIdx.x;
  const f4* xp = (const f4*)(x + ((size_t)b*L_ + (size_t)c*LC) * D_) + t4;
  const f4* ap = (const f4*)(a + ((size_t)b*L_ + (size_t)c*LC) * D_) + t4;
  f4 h = {0.f,0.f,0.f,0.f};
  f4 A = {1.f,1.f,1.f,1.f};
  #pragma unroll 4
  for (int t = 0; t < LC; ++t) {
    f4 av = ap[t*(D_/4)];
    f4 xv = xp[t*(D_/4)];
    h = av*h + xv;
    A = av*A;
  }
  size_t o = ((size_t)c*B_ + b) * (D_/4) + t4;
  ((f4*)sumA)[o] = A;
  ((f4*)sumH)[o] = h;
}

// sequential combine over chunks -> carry-in per chunk
__global__ __launch_bounds__(256) void scan_combine(
    const float* __restrict__ sumA, const float* __restrict__ sumH,
    float* __restrict__ carry) {
  const int id = blockIdx.x*256 + threadIdx.x;    // 0..4095 = (b,d)
  const int b = id >> 10, d = id & (D_-1);
  float H = 0.f;
  for (int c = 0; c < NC; ++c) {
    size_t idx = ((size_t)c*B_ + b)*D_ + d;
    carry[idx] = H;
    H = sumA[idx]*H + sumH[idx];
  }
}

// pass2: recompute with carry-in; fuse out_out = out + h; emit bf16 copy of h
__global__ __launch_bounds__(256) void scan_pass2(
    const float* __restrict__ x, const float* __restrict__ a,
    const float* __restrict__ carry, const float* __restrict__ out_in,
    float* __restrict__ out_out, unsigned short* __restrict__ fbf) {
  const int c = blockIdx.x, b = blockIdx.y;
  const int t4 = threadIdx.x;
  const size_t base4 = (((size_t)b*L_ + (size_t)c*LC) * D_) / 4;
  f4 h = ((const f4*)carry)[((size_t)c*B_ + b)*(D_/4) + t4];
  #pragma unroll 4
  for (int t = 0; t < LC; ++t) {
    size_t o4 = base4 + (size_t)t*(D_/4) + t4;
    f4 av = ((const f4*)a)[o4];
    f4 xv = ((const f4*)x)[o4];
    h = av*h + xv;
    f4 ov = ((const f4*)out_in)[o4];
    ((f4*)out_out)[o4] = ov + h;
    ushort4 hb; hb.x = f2bf(h.x); hb.y = f2bf(h.y); hb.z = f2bf(h.z); hb.w = f2bf(h.w);
    *(ushort4*)&fbf[o4*4] = hb;
  }
}

// ---------------- launch ---------------------------------------------------
extern "C" void kernel_launch(void* const* d_in, const int* in_sizes, int n_in,
                              void* d_out, int out_size, void* d_ws, size_t ws_size,
                              hipStream_t stream) {
  (void)in_sizes; (void)n_in; (void)out_size; (void)ws_size;
  const float* v       = (const float*)d_in[0];
  const float* ctx     = (const float*)d_in[1];
  const float* outp    = (const float*)d_in[2];
  const float* alog    = (const float*)d_in[3];
  const float* g_rms   = (const float*)d_in[4];
  const float* W_alpha = (const float*)d_in[5];
  const float* b_alpha = (const float*)d_in[6];
  const float* W_beta  = (const float*)d_in[7];
  const float* b_beta  = (const float*)d_in[8];
  const float* W_ctx   = (const float*)d_in[9];
  const float* b_ctx   = (const float*)d_in[10];

  float* S0 = (float*)d_out;   // final: v        (written by gemm_ab epilogue)
  float* S1 = S0 + SLOT;       // final: ctx_out  (holds x until gemm_ctx)
  float* S2 = S1 + SLOT;       // final: out_out  (holds ctx_norm bf16 early)
  float* S3 = S2 + SLOT;       // final: alpha_logits (holds alphas early)

  // workspace layout (41 MB total)
  char* w = (char*)d_ws;
  unsigned short* Wab  = (unsigned short*)w;                   // [2048,1024] bf16, 4 MB
  unsigned short* Wct  = (unsigned short*)(w + (size_t)4*1024*1024);   // 2 MB
  unsigned short* fbf  = (unsigned short*)(w + (size_t)6*1024*1024);   // fetched bf16, 32 MB
  float* sumA  = (float*)(w + (size_t)38*1024*1024);           // 1 MB
  float* sumH  = (float*)(w + (size_t)39*1024*1024);           // 1 MB
  float* carry = (float*)(w + (size_t)40*1024*1024);           // 1 MB

  unsigned short* ctxn = (unsigned short*)S2;  // ctx_norm bf16 staged in S2
  float* alphas = S3;
  float* xbuf   = S1;

  transpose_cvt<<<dim3(32,32,3), dim3(32,8), 0, stream>>>(W_alpha, W_beta, W_ctx, Wab, Wct);
  rmsnorm_bf16<<<dim3(M_), dim3(256), 0, stream>>>(ctx, g_rms, ctxn);
  gemm_ab<<<dim3(D_/64, M_/BM), dim3(256), 0, stream>>>(ctxn, Wab,
      b_alpha, b_beta, v, alphas, xbuf, S0);
  scan_pass1<<<dim3(NC, B_), dim3(256), 0, stream>>>(xbuf, alphas, sumA, sumH);
  scan_combine<<<dim3(16), dim3(256), 0, stream>>>(sumA, sumH, carry);
  scan_pass2<<<dim3(NC, B_), dim3(256), 0, stream>>>(xbuf, alphas, carry, outp, S2, fbf);
  gemm128<<<dim3(D_/BN, M_/BM), dim3(256), 0, stream>>>(fbf, Wct,
      EpiCtx{b_ctx, ctx, S1});
  hipMemcpyAsync(S3, alog, SLOT*sizeof(float), hipMemcpyDeviceToDevice, stream);
}